// Round 2
// 331.982 us; speedup vs baseline: 1.0511x; 1.0511x over previous
//
#include <hip/hip_runtime.h>
#include <hip/hip_bf16.h>

#define THREADS 256
#define MTILE   32      // batch rows per block
#define HID     128
#define BATCH   32768
#define NFEAT   8
#define BUFSZ   (MTILE * 136)   // max chunk: DC=128 -> SD=136 (shorts)

typedef __attribute__((ext_vector_type(4))) float f32x4;
typedef __attribute__((ext_vector_type(8))) short s16x8;

struct Ptrs {
    const float* feat[NFEAT];
    const float* wk[NFEAT];
    const float* wv[NFEAT];
    const float* q;
};

__device__ __forceinline__ float bf2f(unsigned short u) {
    union { unsigned int i; float f; } c; c.i = ((unsigned int)u) << 16; return c.f;
}
__device__ __forceinline__ unsigned short f2bf(float f) {
    union { __hip_bfloat16 h; unsigned short u; } c; c.h = __float2bfloat16(f); return c.u;
}

// runtime-indexed copies (prep kernel)
__device__ const int g_fdim[NFEAT] = {32, 64, 96, 128, 192, 256, 384, 512};
__device__ const int g_foff[NFEAT] = {0, 32, 96, 192, 320, 512, 768, 1152};
// compile-time copies (main-kernel templates derive D/FOFF from FI — can't mismatch)
constexpr int c_fdim[NFEAT] = {32, 64, 96, 128, 192, 256, 384, 512};
constexpr int c_foff[NFEAT] = {0, 32, 96, 192, 320, 512, 768, 1152};

// Barrier that does NOT drain vmcnt: staged global loads stay in flight across it.
// Only LDS (lgkm) must be visible to the other waves.
__device__ __forceinline__ void sync_lds() {
    asm volatile("s_waitcnt lgkmcnt(0)" ::: "memory");
    __builtin_amdgcn_s_barrier();
    asm volatile("" ::: "memory");
}

// ---------------- fused prep: Wv -> bf16 B-fragment layout, and qk = (Wk^T q)/sqrt(128) ----------------
__global__ void prep_all(Ptrs p, unsigned short* WvB, float* qk) {
    int bid = blockIdx.x;
    if (bid < NFEAT * 8) {
        int fi    = bid >> 3;
        int slice = bid & 7;
        int D  = g_fdim[fi];
        int Dg = D >> 3;
        const float* Wv = p.wv[fi];
        unsigned short* out = WvB + 128 * g_foff[fi];
        int h0  = slice * 16;
        int cnt = 16 * Dg;
        for (int e = threadIdx.x; e < cnt; e += blockDim.x) {
            int h  = h0 + e / Dg;
            int kg = e - (e / Dg) * Dg;
            const float* src = Wv + h * D + kg * 8;
            float4 x = *reinterpret_cast<const float4*>(src);
            float4 y = *reinterpret_cast<const float4*>(src + 4);
            s16x8 b;
            b[0] = (short)f2bf(x.x); b[1] = (short)f2bf(x.y);
            b[2] = (short)f2bf(x.z); b[3] = (short)f2bf(x.w);
            b[4] = (short)f2bf(y.x); b[5] = (short)f2bf(y.y);
            b[6] = (short)f2bf(y.z); b[7] = (short)f2bf(y.w);
            *reinterpret_cast<s16x8*>(out + (kg * 128 + h) * 8) = b;
        }
    } else {
        int i = bid - NFEAT * 8;
        int d = g_fdim[i];
        const float* Wk = p.wk[i];
        const float* q  = p.q;
        for (int c = threadIdx.x; c < d; c += blockDim.x) {
            float s = 0.f;
            #pragma unroll 8
            for (int h = 0; h < HID; ++h) s = fmaf(q[h], Wk[h * d + c], s);
            qk[g_foff[i] + c] = s * 0.08838834764831845f;   // 1/sqrt(128)
        }
    }
}

// ---------------- main kernel pieces ----------------
template<int FI, int CK0, int DC>
__device__ __forceinline__ void stage_issue(const Ptrs& p, int row0, int tid, float4* regs) {
    constexpr int D = c_fdim[FI];          // row stride derived from FI — cannot mismatch
    const float* fbase = p.feat[FI] + (size_t)row0 * D + CK0;
    constexpr int NITER = (MTILE * DC / 4) / THREADS;   // <= 4
    #pragma unroll
    for (int jj = 0; jj < NITER; ++jj) {
        int flat = (tid + jj * THREADS) * 4;
        int r = flat / DC;
        int c = flat - r * DC;
        regs[jj] = *reinterpret_cast<const float4*>(fbase + (size_t)r * D + c);
    }
}

template<int DC>
__device__ __forceinline__ void stage_commit(const float4* regs, unsigned short* A, int tid) {
    constexpr int SD = DC + 8;
    constexpr int NITER = (MTILE * DC / 4) / THREADS;
    #pragma unroll
    for (int jj = 0; jj < NITER; ++jj) {
        int flat = (tid + jj * THREADS) * 4;
        int r = flat / DC;
        int c = flat - r * DC;
        float4 v = regs[jj];
        ushort4 u;
        u.x = f2bf(v.x); u.y = f2bf(v.y); u.z = f2bf(v.z); u.w = f2bf(v.w);
        *reinterpret_cast<ushort4*>(&A[r * SD + c]) = u;
    }
}

template<int FI, int CK0, int DC, bool FIRST, bool LAST>
__device__ __forceinline__ void compute_chunk(
    const unsigned short* A, const unsigned short* WvB, const float* qkS,
    float* wAll, float* Zrow, float& spart,
    f32x4 (&P)[2][2], f32x4 (&O)[2][2],
    int tid, int wave, int l15, int q4)
{
    constexpr int FOFF = c_foff[FI];       // derived from FI — cannot mismatch
    constexpr int SD = DC + 8;
    if (FIRST) {
        spart = 0.f;
        #pragma unroll
        for (int mt = 0; mt < 2; ++mt) {
            P[mt][0] = f32x4{0.f, 0.f, 0.f, 0.f};
            P[mt][1] = f32x4{0.f, 0.f, 0.f, 0.f};
        }
    }

    // ---- score partial: 8 threads per row, LDS-only (qk lives in LDS) ----
    {
        int r = tid >> 3, part = tid & 7;
        constexpr int Q = DC / 8;   // multiple of 4
        const float* qf = qkS + FOFF + CK0 + part * Q;
        const unsigned short* arow = A + r * SD + part * Q;
        float acc = 0.f;
        #pragma unroll
        for (int c = 0; c < Q; c += 4) {
            ushort4 u  = *reinterpret_cast<const ushort4*>(arow + c);
            float4  qv = *reinterpret_cast<const float4*>(qf + c);
            acc += bf2f(u.x) * qv.x + bf2f(u.y) * qv.y +
                   bf2f(u.z) * qv.z + bf2f(u.w) * qv.w;
        }
        spart += acc;
    }

    // ---- MFMA: P += A @ Wv^T (B pre-converted bf16, fragment layout, L2-hot) ----
    {
        const unsigned short* Wb = WvB + 128 * FOFF;
        #pragma unroll
        for (int kk = 0; kk < DC / 32; ++kk) {
            int kg = CK0 / 8 + kk * 4 + q4;
            int hb = wave * 32 + l15;
            s16x8 b0 = *reinterpret_cast<const s16x8*>(Wb + (kg * 128 + hb) * 8);
            s16x8 b1 = *reinterpret_cast<const s16x8*>(Wb + (kg * 128 + hb + 16) * 8);
            int k0 = kk * 32 + q4 * 8;
            #pragma unroll
            for (int mt = 0; mt < 2; ++mt) {
                s16x8 a = *reinterpret_cast<const s16x8*>(A + (mt * 16 + l15) * SD + k0);
                P[mt][0] = __builtin_amdgcn_mfma_f32_16x16x32_bf16(a, b0, P[mt][0], 0, 0, 0);
                P[mt][1] = __builtin_amdgcn_mfma_f32_16x16x32_bf16(a, b1, P[mt][1], 0, 0, 0);
            }
        }
    }

    if (LAST) {
        float s = spart;
        s += __shfl_xor(s, 1, 64);
        s += __shfl_xor(s, 2, 64);
        s += __shfl_xor(s, 4, 64);
        int r = tid >> 3;
        if ((tid & 7) == 0) {
            float w = __expf(s);        // scores ~ N(0,1/3): no max-subtraction needed
            wAll[FI * MTILE + r] = w;
            Zrow[r] += w;
        }
        sync_lds();
        #pragma unroll
        for (int mt = 0; mt < 2; ++mt) {
            #pragma unroll
            for (int rr = 0; rr < 4; ++rr) {
                // C/D layout: col = lane&15, row = quad*4 + reg
                float w = wAll[FI * MTILE + mt * 16 + q4 * 4 + rr];
                O[mt][0][rr] += w * P[mt][0][rr];
                O[mt][1][rr] += w * P[mt][1][rr];
            }
        }
    }
}

__global__ __launch_bounds__(THREADS, 4)
void attn_main(Ptrs p, const unsigned short* WvB, const float* qk,
               float* outC, float* outA) {
    __shared__ __align__(16) unsigned short Abuf[2 * BUFSZ];   // 17.0 KB
    __shared__ __align__(16) float qkS[1664];                  // 6.5 KB
    __shared__ float wAll[NFEAT * MTILE];
    __shared__ float Zrow[MTILE];
    unsigned short* buf0 = Abuf;
    unsigned short* buf1 = Abuf + BUFSZ;

    int tid  = threadIdx.x;
    int wave = tid >> 6;
    int lane = tid & 63;
    int l15  = lane & 15, q4 = lane >> 4;
    int row0 = blockIdx.x * MTILE;

    for (int g = tid; g < 1664; g += THREADS) qkS[g] = qk[g];
    if (tid < MTILE) Zrow[tid] = 0.f;

    f32x4 P[2][2], O[2][2];
    #pragma unroll
    for (int mt = 0; mt < 2; ++mt) {
        O[mt][0] = f32x4{0.f, 0.f, 0.f, 0.f};
        O[mt][1] = f32x4{0.f, 0.f, 0.f, 0.f};
    }
    float spart = 0.f;
    float4 rA[4], rB[4];

#define ISSUE(FI,CK0,DC,R)                stage_issue<FI,CK0,DC>(p, row0, tid, R)
#define COMMIT(DC,R,BUF)                  stage_commit<DC>(R, BUF, tid)
#define COMP(FI,CK0,DC,FIRST,LAST,BUF) \
    compute_chunk<FI,CK0,DC,FIRST,LAST>(BUF, WvB, qkS, wAll, Zrow, spart, P, O, tid, wave, l15, q4)
#define SB()                              __builtin_amdgcn_sched_barrier(0)

    // 15 uniform chunks (DC <= 128), chunk c lives in buf(c%2) / regs ping-pong.
    // Per iter k: COMP(k) [its B/qk traffic precedes newer staging in the
    // in-order vmcnt queue] ; ISSUE(k+2) ; COMMIT(k+1) [compiler emits a
    // counted vmcnt that waits only chunk k+1, issued a full iter earlier] ;
    // non-draining barrier. Staged loads survive every barrier.

    ISSUE(0,   0,  32, rA);  ISSUE(1,   0,  64, rB);
    COMMIT(32, rA, buf0);
    sync_lds();

    COMP(0,   0,  32, true,  true,  buf0); SB(); ISSUE(2,   0,  96, rA); SB(); COMMIT( 64, rB, buf1); sync_lds();
    COMP(1,   0,  64, true,  true,  buf1); SB(); ISSUE(3,   0, 128, rB); SB(); COMMIT( 96, rA, buf0); sync_lds();
    COMP(2,   0,  96, true,  true,  buf0); SB(); ISSUE(4,   0,  96, rA); SB(); COMMIT(128, rB, buf1); sync_lds();
    COMP(3,   0, 128, true,  true,  buf1); SB(); ISSUE(4,  96,  96, rB); SB(); COMMIT( 96, rA, buf0); sync_lds();
    COMP(4,   0,  96, true,  false, buf0); SB(); ISSUE(5,   0, 128, rA); SB(); COMMIT( 96, rB, buf1); sync_lds();
    COMP(4,  96,  96, false, true,  buf1); SB(); ISSUE(5, 128, 128, rB); SB(); COMMIT(128, rA, buf0); sync_lds();
    COMP(5,   0, 128, true,  false, buf0); SB(); ISSUE(6,   0, 128, rA); SB(); COMMIT(128, rB, buf1); sync_lds();
    COMP(5, 128, 128, false, true,  buf1); SB(); ISSUE(6, 128, 128, rB); SB(); COMMIT(128, rA, buf0); sync_lds();
    COMP(6,   0, 128, true,  false, buf0); SB(); ISSUE(6, 256, 128, rA); SB(); COMMIT(128, rB, buf1); sync_lds();
    COMP(6, 128, 128, false, false, buf1); SB(); ISSUE(7,   0, 128, rB); SB(); COMMIT(128, rA, buf0); sync_lds();
    COMP(6, 256, 128, false, true,  buf0); SB(); ISSUE(7, 128, 128, rA); SB(); COMMIT(128, rB, buf1); sync_lds();
    COMP(7,   0, 128, true,  false, buf1); SB(); ISSUE(7, 256, 128, rB); SB(); COMMIT(128, rA, buf0); sync_lds();
    COMP(7, 128, 128, false, false, buf0); SB(); ISSUE(7, 384, 128, rA); SB(); COMMIT(128, rB, buf1); sync_lds();
    COMP(7, 256, 128, false, false, buf1); SB();                               COMMIT(128, rA, buf0); sync_lds();
    COMP(7, 384, 128, false, true,  buf0);

    // ---- epilogue: transpose O through LDS, coalesced float4 stores ----
    sync_lds();                             // all waves done with buf0
    float* Ctmp = reinterpret_cast<float*>(Abuf);   // 32 x 136 fp32 = 17.0 KB (fits exactly)
    #pragma unroll
    for (int mt = 0; mt < 2; ++mt) {
        #pragma unroll
        for (int rr = 0; rr < 4; ++rr) {
            int row = mt * 16 + q4 * 4 + rr;
            float zi = 1.0f / Zrow[row];
            Ctmp[row * 136 + wave * 32 + l15]      = O[mt][0][rr] * zi;
            Ctmp[row * 136 + wave * 32 + 16 + l15] = O[mt][1][rr] * zi;
        }
    }
    sync_lds();
    #pragma unroll
    for (int it = 0; it < 4; ++it) {
        int j = tid + it * THREADS;        // 0..1023 = 32 rows x 32 float4
        int r = j >> 5, c4 = (j & 31) * 4;
        *reinterpret_cast<float4*>(outC + (size_t)(row0 + r) * HID + c4) =
            *reinterpret_cast<const float4*>(Ctmp + r * 136 + c4);
    }
    if (tid < MTILE) {
        float zi = 1.0f / Zrow[tid];
        float4 a0, a1;
        a0.x = wAll[0 * MTILE + tid] * zi; a0.y = wAll[1 * MTILE + tid] * zi;
        a0.z = wAll[2 * MTILE + tid] * zi; a0.w = wAll[3 * MTILE + tid] * zi;
        a1.x = wAll[4 * MTILE + tid] * zi; a1.y = wAll[5 * MTILE + tid] * zi;
        a1.z = wAll[6 * MTILE + tid] * zi; a1.w = wAll[7 * MTILE + tid] * zi;
        float* dst = outA + (size_t)(row0 + tid) * NFEAT;
        *reinterpret_cast<float4*>(dst)     = a0;
        *reinterpret_cast<float4*>(dst + 4) = a1;
    }
#undef ISSUE
#undef COMMIT
#undef COMP
#undef SB
}

extern "C" void kernel_launch(void* const* d_in, const int* in_sizes, int n_in,
                              void* d_out, int out_size, void* d_ws, size_t ws_size,
                              hipStream_t stream) {
    Ptrs p;
    // setup_inputs() dict order: feat0..feat7, then Wk0,Wv0,Wk1,Wv1,... (interleaved), then query
    for (int i = 0; i < NFEAT; ++i) {
        p.feat[i] = (const float*)d_in[i];
        p.wk[i]   = (const float*)d_in[NFEAT + 2 * i];
        p.wv[i]   = (const float*)d_in[NFEAT + 2 * i + 1];
    }
    p.q = (const float*)d_in[3 * NFEAT];

    // workspace layout: [WvB bf16: 128*1664*2 = 425984 B][qk fp32: 1664*4 B]
    unsigned short* WvB = (unsigned short*)d_ws;
    float* qk = (float*)((char*)d_ws + 128 * 1664 * 2);

    prep_all<<<NFEAT * 8 + NFEAT, 256, 0, stream>>>(p, WvB, qk);

    float* outC = (float*)d_out;
    float* outA = outC + (size_t)BATCH * HID;
    attn_main<<<BATCH / MTILE, THREADS, 0, stream>>>(p, WvB, qk, outC, outA);
}